// Round 3
// baseline (746.117 us; speedup 1.0000x reference)
//
#include <hip/hip_runtime.h>

#define NKER 84
#define NCH 9
#define SEQ 2048
#define NBATCH 64
#define NDIL 26
#define NFTOT 9996
#define MAXNF 15
#define NSLOT 12
#define NXCD 8

// Static MiniRocket config for SEQ_LEN=2048, NUM_FEATURES=10000 (replicates numpy float64 logspace)
static constexpr int DILS[NDIL]   = {1,2,3,4,5,7,8,10,12,14,17,20,25,29,35,42,51,61,73,87,104,125,149,178,213,255};
static constexpr int NFDS[NDIL]   = {15,12,4,4,8,4,4,4,4,4,4,4,4,4,4,4,4,4,3,3,3,3,3,3,3,3};
static constexpr int CBASES[NDIL] = {0,1260,2268,2604,2940,3612,3948,4284,4620,4956,5292,5628,5964,6300,6636,6972,7308,7644,7980,8232,8484,8736,8988,9240,9492,9744};

// 2-float vector with 4-byte alignment: legal at odd dword offsets; compiler
// emits ds_read_b64 (aligned) or ds_read2_b32 offset0/offset1 (unaligned) —
// one DS instruction for two consecutive taps' elements either way.
// (Round-1/2 lesson: the b128 quad variant raised bank conflicts 3.7x and its
// register pressure triggered the spill catastrophe — stay at x2.)
typedef float f32x2u __attribute__((ext_vector_type(2), aligned(4)));

// Force a (known-uniform) float into an SGPR so v_cmp reads it scalar-side.
__device__ __forceinline__ float uniform_f(float v) {
    return __builtin_bit_cast(float, __builtin_amdgcn_readfirstlane(__builtin_bit_cast(int, v)));
}

template <int I>
__device__ __forceinline__ void body(const float* __restrict__ kw,
                                     const float* __restrict__ cc,
                                     const float* __restrict__ bias,
                                     float* __restrict__ out,
                                     const float* __restrict__ xb,   // x + b*NCH*SEQ
                                     float* __restrict__ y,
                                     int b, int slot, int lane) {
    constexpr int D = DILS[I];
    constexpr int NF = NFDS[I];
    constexpr int P = 4 * D;
    constexpr int PAD1 = I & 1;
    constexpr int CBASE = CBASES[I];
    constexpr int RANGE = SEQ - 2 * P;          // valid-region length (>0 for all D)
    // full-range loop split (compile-time): interior j has all taps in [0, SEQ) for every lane
    constexpr int JLO = (P + 63) / 64;                      // first fully-interior 64-iter
    constexpr int JHI = (SEQ - P - 64) / 64;                // last fully-interior 64-iter (incl)
    constexpr int NI  = (JHI + 1 > JLO) ? (JHI + 1 - JLO) : 0;   // # interior 64-iters
    constexpr int NI2 = NI / 2;                             // 128-el pair-iters
    constexpr bool IBR = (NI & 1) != 0;                     // one bridge 64-iter
    constexpr int JT0 = (JHI + 1 > JLO) ? (JHI + 1) : JLO;  // start of trailing boundary
    // valid-region decomposition: pairs + optional 64-bridge + clamped partial
    constexpr int MV2 = RANGE / 128;
    constexpr int TV1 = (RANGE - MV2 * 128) / 64;           // 0 or 1
    constexpr int REM = RANGE - MV2 * 128 - TV1 * 64;       // 0..63

    const float4* __restrict__ xb4 = (const float4*)xb;     // [NCH][SEQ/4]

    for (int k = slot; k < NKER; k += NSLOT) {
        // ---- per-kernel config (wave-uniform scalars) ----
        int mb = 0;
        for (int c = 0; c < NCH; ++c)
            if (cc[(I * NCH + c) * NKER + k] != 0.0f) mb |= (1 << c);
        mb = __builtin_amdgcn_readfirstlane(mb);

        int j0 = -1, j1 = -1, j2 = -1, no = 0;
        for (int j = 0; j < 9; ++j) {
            if (kw[k * 9 + j] > 0.0f) {
                if (no == 0) j0 = j; else if (no == 1) j1 = j; else j2 = j;
                ++no;
            }
        }
        j0 = __builtin_amdgcn_readfirstlane(j0);
        j1 = __builtin_amdgcn_readfirstlane(j1);
        j2 = __builtin_amdgcn_readfirstlane(j2);

        float w[9];
#pragma unroll
        for (int jj = 0; jj < 9; ++jj)
            w[jj] = (jj == j0 || jj == j1 || jj == j2) ? 2.0f : -1.0f;

        float bs[NF];
#pragma unroll
        for (int f = 0; f < NF; ++f)
            bs[f] = uniform_f(bias[(I * NKER + k) * MAXNF + f]);

        // ---- build y[t] = sum of masked channels, two half-SEQ passes ----
#pragma unroll
        for (int h = 0; h < 2; ++h) {
            float4 acc[SEQ / 512];
#pragma unroll
            for (int it = 0; it < SEQ / 512; ++it)
                acc[it] = make_float4(0.f, 0.f, 0.f, 0.f);
#pragma unroll
            for (int c = 0; c < NCH; ++c) {
                if (mb & (1 << c)) {
#pragma unroll
                    for (int it = 0; it < SEQ / 512; ++it) {
                        float4 v = xb4[c * (SEQ / 4) + h * (SEQ / 8) + it * 64 + lane];
                        acc[it].x += v.x; acc[it].y += v.y; acc[it].z += v.z; acc[it].w += v.w;
                    }
                }
            }
#pragma unroll
            for (int it = 0; it < SEQ / 512; ++it)
                ((float4*)y)[h * (SEQ / 8) + it * 64 + lane] = acc[it];
        }

        // wave-total counters: ballot+popcount accumulates in scalar regs
        // (v_cmp wave-wide -> s_bcnt1/s_add on the scalar pipe; deletes the
        // per-feature VGPR counters and the final 6-step shuffle reduce)
        int cnt[NF];
#pragma unroll
        for (int f = 0; f < NF; ++f) cnt[f] = 0;

        // 128-el pair iter: lane handles t=TB+2*lane and t+1; per tap one 2-dword load
#define MRF_ITER2(TB) { \
            const int e0_ = (TB) + 2 * lane - 4 * D; \
            float CvA = 0.0f, CvB = 0.0f; \
            _Pragma("unroll") \
            for (int jj = 0; jj < 9; ++jj) { \
                f32x2u p_ = *(const f32x2u*)(y + e0_ + jj * D); \
                CvA = __builtin_fmaf(w[jj], p_.x, CvA); \
                CvB = __builtin_fmaf(w[jj], p_.y, CvB); \
            } \
            _Pragma("unroll") \
            for (int f = 0; f < NF; ++f) \
                cnt[f] += __popcll(__ballot(CvA > bs[f])) + __popcll(__ballot(CvB > bs[f])); }

        // 64-el unmasked iter
#define MRF_ITER(TB) { \
            const int t_ = (TB) + lane; \
            float Cv = 0.0f; \
            _Pragma("unroll") \
            for (int jj = 0; jj < 9; ++jj) \
                Cv = __builtin_fmaf(w[jj], y[t_ + (jj - 4) * D], Cv); \
            _Pragma("unroll") \
            for (int f = 0; f < NF; ++f) \
                cnt[f] += __popcll(__ballot(Cv > bs[f])); }

        // 64-el boundary iter: per-tap window is WAVE-UNIFORM in/out/straddle ->
        // compile-time skip (out), plain fma (in), clamped load only when straddling
#define MRF_MASKED(TB) { \
            const int t_ = (TB) + lane; \
            float Cv = 0.0f; \
            _Pragma("unroll") \
            for (int jj = 0; jj < 9; ++jj) { \
                const int lo_ = (TB) + (jj - 4) * D; \
                if (lo_ >= 0 && lo_ + 63 < SEQ) { \
                    Cv = __builtin_fmaf(w[jj], y[t_ + (jj - 4) * D], Cv); \
                } else if (lo_ + 63 >= 0 && lo_ < SEQ) { \
                    const int u_ = t_ + (jj - 4) * D; \
                    float v_ = y[u_ & (SEQ - 1)]; \
                    v_ = ((unsigned)u_ < (unsigned)SEQ) ? v_ : 0.0f; \
                    Cv = __builtin_fmaf(w[jj], v_, Cv); \
                } \
            } \
            _Pragma("unroll") \
            for (int f = 0; f < NF; ++f) \
                cnt[f] += __popcll(__ballot(Cv > bs[f])); }

        if ((k & 1) == PAD1) {
            // ===== full padded range [0, SEQ): masked lead, paired interior, masked trail =====
#pragma unroll 4
            for (int j = 0; j < JLO; ++j) MRF_MASKED(j * 64)
#pragma unroll 2
            for (int a = 0; a < NI2; ++a) MRF_ITER2(JLO * 64 + a * 128)
            if constexpr (IBR) MRF_ITER(JLO * 64 + NI2 * 128)
#pragma unroll 4
            for (int j = JT0; j < SEQ / 64; ++j) MRF_MASKED(j * 64)
        } else {
            // ===== valid region [P, SEQ-P): paired main, bridge, clamped partial =====
#pragma unroll 2
            for (int a = 0; a < MV2; ++a) MRF_ITER2(P + a * 128)
            if constexpr (TV1) MRF_ITER(P + MV2 * 128)
            if constexpr (REM != 0) {   // final partial, clamped reads, poisoned lanes
                const int t = P + MV2 * 128 + TV1 * 64 + lane;
                const int tr = (t < SEQ - P) ? t : (SEQ - P - 1);
                const float* __restrict__ pb = y + tr - 4 * D;
                float Cv = 0.0f;
#pragma unroll
                for (int jj = 0; jj < 9; ++jj)
                    Cv = __builtin_fmaf(w[jj], pb[jj * D], Cv);
                Cv = (t < SEQ - P) ? Cv : -3.402823466e38f;   // poison -> never > bias
#pragma unroll
                for (int f = 0; f < NF; ++f)
                    cnt[f] += __popcll(__ballot(Cv > bs[f]));
            }
        }

#undef MRF_ITER2
#undef MRF_ITER
#undef MRF_MASKED

        // ---- write (cnt[] is already the wave total; no shuffle reduce) ----
        const bool full = ((k & 1) == PAD1);
        const float invT = full ? (1.0f / (float)SEQ) : (1.0f / (float)RANGE);
        const int pos = full ? ((k - PAD1) >> 1) : (42 + ((k - (1 - PAD1)) >> 1));
        const int colb = CBASE + pos * NF;
        if (lane == 0) {
#pragma unroll
            for (int f = 0; f < NF; ++f)
                out[(size_t)b * NFTOT + colb + f] = (float)cnt[f] * invT;
        }
    }
}

// NOTE: plain __launch_bounds__(64). Round-1/2 lesson: adding a min-waves/EU
// arg (64,4) made the allocator clamp to the 64-VGPR occupancy step and spill
// ~400 MB/dispatch to scratch (WRITE_SIZE 2.5MB -> 404MB, FETCH 5.7MB -> 689MB).
extern "C" __global__ void __launch_bounds__(64)
mrf_kernel(const float* __restrict__ x, const float* __restrict__ kw,
           const float* __restrict__ cc, const float* __restrict__ bias,
           float* __restrict__ out) {
    __shared__ __align__(16) float ybuf[SEQ];   // 8 KB per 1-wave block

    // XCD-chunked bijective swizzle (proven round 0): XCD x owns a contiguous
    // chunk of (b,i,s) with b slowest -> concurrent blocks on an XCD share ~1-2
    // b values -> x slices stay L2-resident. Round-1 measured the alternative
    // (i slowest): per-XCD working set = all 64 b slices > 4 MB L2 -> 1.75 GB
    // of L2 misses, 1.7x slower.
    constexpr int NGRID = NDIL * NBATCH * NSLOT;       // 19968
    constexpr int CHUNK = NGRID / NXCD;                // 2496
    const int blk = (blockIdx.x % NXCD) * CHUNK + blockIdx.x / NXCD;

    const int s = blk % NSLOT;
    const int rest = blk / NSLOT;
    const int i = rest % NDIL;              // dilation index
    const int b = rest / NDIL;              // batch index (slowest)
    const int lane = threadIdx.x & 63;

    const float* xb = x + (size_t)b * (NCH * SEQ);

    switch (i) {
#define MRF_CASE(I) case I: body<I>(kw, cc, bias, out, xb, ybuf, b, s, lane); break;
        MRF_CASE(0)  MRF_CASE(1)  MRF_CASE(2)  MRF_CASE(3)  MRF_CASE(4)
        MRF_CASE(5)  MRF_CASE(6)  MRF_CASE(7)  MRF_CASE(8)  MRF_CASE(9)
        MRF_CASE(10) MRF_CASE(11) MRF_CASE(12) MRF_CASE(13) MRF_CASE(14)
        MRF_CASE(15) MRF_CASE(16) MRF_CASE(17) MRF_CASE(18) MRF_CASE(19)
        MRF_CASE(20) MRF_CASE(21) MRF_CASE(22) MRF_CASE(23) MRF_CASE(24)
        MRF_CASE(25)
#undef MRF_CASE
    }
}

extern "C" void kernel_launch(void* const* d_in, const int* in_sizes, int n_in,
                              void* d_out, int out_size, void* d_ws, size_t ws_size,
                              hipStream_t stream) {
    (void)in_sizes; (void)n_in; (void)d_ws; (void)ws_size; (void)out_size;
    const float* x    = (const float*)d_in[0];
    const float* kw   = (const float*)d_in[1];
    const float* cc   = (const float*)d_in[2];
    const float* bias = (const float*)d_in[3];
    float* out = (float*)d_out;

    mrf_kernel<<<dim3(NDIL * NBATCH * NSLOT), dim3(64), 0, stream>>>(x, kw, cc, bias, out);
}

// Round 4
// 744.852 us; speedup vs baseline: 1.0017x; 1.0017x over previous
//
#include <hip/hip_runtime.h>

#define NKER 84
#define NCH 9
#define SEQ 2048
#define NBATCH 64
#define NDIL 26
#define NFTOT 9996
#define MAXNF 15
#define NSLOT 12
#define NXCD 8

// Static MiniRocket config for SEQ_LEN=2048, NUM_FEATURES=10000 (replicates numpy float64 logspace)
static constexpr int DILS[NDIL]   = {1,2,3,4,5,7,8,10,12,14,17,20,25,29,35,42,51,61,73,87,104,125,149,178,213,255};
static constexpr int NFDS[NDIL]   = {15,12,4,4,8,4,4,4,4,4,4,4,4,4,4,4,4,4,3,3,3,3,3,3,3,3};
static constexpr int CBASES[NDIL] = {0,1260,2268,2604,2940,3612,3948,4284,4620,4956,5292,5628,5964,6300,6636,6972,7308,7644,7980,8232,8484,8736,8988,9240,9492,9744};

// 2-float vector with 4-byte alignment: legal at odd dword offsets; compiler
// emits ds_read_b64 (aligned) or ds_read2_b32 offset0/offset1 (unaligned) —
// one DS instruction for two consecutive taps' elements either way.
// (Round-1/2 lesson: the b128 quad variant raised bank conflicts 3.7x and its
// register pressure triggered a 400MB scratch-spill catastrophe — stay at x2.)
typedef float f32x2u __attribute__((ext_vector_type(2), aligned(4)));

template <int I>
__device__ __forceinline__ void body(const float* __restrict__ kw,
                                     const float* __restrict__ cc,
                                     const float* __restrict__ bias,
                                     float* __restrict__ out,
                                     const float* __restrict__ xb,   // x + b*NCH*SEQ
                                     float* __restrict__ y,
                                     int b, int slot, int lane) {
    constexpr int D = DILS[I];
    constexpr int NF = NFDS[I];
    constexpr int P = 4 * D;
    constexpr int PAD1 = I & 1;
    constexpr int CBASE = CBASES[I];
    constexpr int RANGE = SEQ - 2 * P;          // valid-region length (>0 for all D)
    // full-range loop split (compile-time): interior j has all taps in [0, SEQ) for every lane
    constexpr int JLO = (P + 63) / 64;                      // first fully-interior 64-iter
    constexpr int JHI = (SEQ - P - 64) / 64;                // last fully-interior 64-iter (incl)
    constexpr int NI  = (JHI + 1 > JLO) ? (JHI + 1 - JLO) : 0;   // # interior 64-iters
    constexpr int NI2 = NI / 2;                             // 128-el pair-iters
    constexpr bool IBR = (NI & 1) != 0;                     // one bridge 64-iter
    constexpr int JT0 = (JHI + 1 > JLO) ? (JHI + 1) : JLO;  // start of trailing boundary
    // valid-region decomposition: pairs + optional 64-bridge + clamped partial
    constexpr int MV2 = RANGE / 128;
    constexpr int TV1 = (RANGE - MV2 * 128) / 64;           // 0 or 1
    constexpr int REM = RANGE - MV2 * 128 - TV1 * 64;       // 0..63

    const float4* __restrict__ xb4 = (const float4*)xb;     // [NCH][SEQ/4]

    for (int k = slot; k < NKER; k += NSLOT) {
        // ---- per-kernel config (wave-uniform scalars) ----
        int mb = 0;
        for (int c = 0; c < NCH; ++c)
            if (cc[(I * NCH + c) * NKER + k] != 0.0f) mb |= (1 << c);
        mb = __builtin_amdgcn_readfirstlane(mb);

        int j0 = -1, j1 = -1, j2 = -1, no = 0;
        for (int j = 0; j < 9; ++j) {
            if (kw[k * 9 + j] > 0.0f) {
                if (no == 0) j0 = j; else if (no == 1) j1 = j; else j2 = j;
                ++no;
            }
        }
        j0 = __builtin_amdgcn_readfirstlane(j0);
        j1 = __builtin_amdgcn_readfirstlane(j1);
        j2 = __builtin_amdgcn_readfirstlane(j2);

        float w[9];
#pragma unroll
        for (int jj = 0; jj < 9; ++jj)
            w[jj] = (jj == j0 || jj == j1 || jj == j2) ? 2.0f : -1.0f;

        // bias thresholds stay in VGPRs (round-0 style): v_cmp reads them at
        // full rate, and NOT freeing these registers keeps the allocator at the
        // known-good <=128-VGPR bucket (round-3 lesson: freeing slack let the
        // scheduler drift to 144 VGPR -> occupancy bucket halved -> 1.6x slower).
        float bs[NF];
#pragma unroll
        for (int f = 0; f < NF; ++f) bs[f] = bias[(I * NKER + k) * MAXNF + f];

        // ---- build y[t] = sum of masked channels, two half-SEQ passes ----
#pragma unroll
        for (int h = 0; h < 2; ++h) {
            float4 acc[SEQ / 512];
#pragma unroll
            for (int it = 0; it < SEQ / 512; ++it)
                acc[it] = make_float4(0.f, 0.f, 0.f, 0.f);
#pragma unroll
            for (int c = 0; c < NCH; ++c) {
                if (mb & (1 << c)) {
#pragma unroll
                    for (int it = 0; it < SEQ / 512; ++it) {
                        float4 v = xb4[c * (SEQ / 4) + h * (SEQ / 8) + it * 64 + lane];
                        acc[it].x += v.x; acc[it].y += v.y; acc[it].z += v.z; acc[it].w += v.w;
                    }
                }
            }
#pragma unroll
            for (int it = 0; it < SEQ / 512; ++it)
                ((float4*)y)[h * (SEQ / 8) + it * 64 + lane] = acc[it];
        }

        // wave-total counters via ballot+popcount: one v_cmp per (element,f)
        // (vs cmp+add in round 0), accumulate on the scalar pipe, and the final
        // 6-step shuffle reduce is deleted. Proven -16% per-wave (round 3).
        int cnt[NF];
#pragma unroll
        for (int f = 0; f < NF; ++f) cnt[f] = 0;

        // 128-el pair iter: lane handles t=TB+2*lane and t+1; per tap one 2-dword load
#define MRF_ITER2(TB) { \
            const int e0_ = (TB) + 2 * lane - 4 * D; \
            float CvA = 0.0f, CvB = 0.0f; \
            _Pragma("unroll") \
            for (int jj = 0; jj < 9; ++jj) { \
                f32x2u p_ = *(const f32x2u*)(y + e0_ + jj * D); \
                CvA = __builtin_fmaf(w[jj], p_.x, CvA); \
                CvB = __builtin_fmaf(w[jj], p_.y, CvB); \
            } \
            _Pragma("unroll") \
            for (int f = 0; f < NF; ++f) \
                cnt[f] += __popcll(__ballot(CvA > bs[f])) + __popcll(__ballot(CvB > bs[f])); }

        // 64-el unmasked iter
#define MRF_ITER(TB) { \
            const int t_ = (TB) + lane; \
            float Cv = 0.0f; \
            _Pragma("unroll") \
            for (int jj = 0; jj < 9; ++jj) \
                Cv = __builtin_fmaf(w[jj], y[t_ + (jj - 4) * D], Cv); \
            _Pragma("unroll") \
            for (int f = 0; f < NF; ++f) \
                cnt[f] += __popcll(__ballot(Cv > bs[f])); }

        // 64-el boundary iter: per-tap window is WAVE-UNIFORM in/out/straddle ->
        // compile-time skip (out), plain fma (in), clamped load only when straddling
#define MRF_MASKED(TB) { \
            const int t_ = (TB) + lane; \
            float Cv = 0.0f; \
            _Pragma("unroll") \
            for (int jj = 0; jj < 9; ++jj) { \
                const int lo_ = (TB) + (jj - 4) * D; \
                if (lo_ >= 0 && lo_ + 63 < SEQ) { \
                    Cv = __builtin_fmaf(w[jj], y[t_ + (jj - 4) * D], Cv); \
                } else if (lo_ + 63 >= 0 && lo_ < SEQ) { \
                    const int u_ = t_ + (jj - 4) * D; \
                    float v_ = y[u_ & (SEQ - 1)]; \
                    v_ = ((unsigned)u_ < (unsigned)SEQ) ? v_ : 0.0f; \
                    Cv = __builtin_fmaf(w[jj], v_, Cv); \
                } \
            } \
            _Pragma("unroll") \
            for (int f = 0; f < NF; ++f) \
                cnt[f] += __popcll(__ballot(Cv > bs[f])); }

        if ((k & 1) == PAD1) {
            // ===== full padded range [0, SEQ): masked lead, paired interior, masked trail =====
#pragma unroll 4
            for (int j = 0; j < JLO; ++j) MRF_MASKED(j * 64)
#pragma unroll 2
            for (int a = 0; a < NI2; ++a) MRF_ITER2(JLO * 64 + a * 128)
            if constexpr (IBR) MRF_ITER(JLO * 64 + NI2 * 128)
#pragma unroll 4
            for (int j = JT0; j < SEQ / 64; ++j) MRF_MASKED(j * 64)
        } else {
            // ===== valid region [P, SEQ-P): paired main, bridge, clamped partial =====
#pragma unroll 2
            for (int a = 0; a < MV2; ++a) MRF_ITER2(P + a * 128)
            if constexpr (TV1) MRF_ITER(P + MV2 * 128)
            if constexpr (REM != 0) {   // final partial, clamped reads, poisoned lanes
                const int t = P + MV2 * 128 + TV1 * 64 + lane;
                const int tr = (t < SEQ - P) ? t : (SEQ - P - 1);
                const float* __restrict__ pb = y + tr - 4 * D;
                float Cv = 0.0f;
#pragma unroll
                for (int jj = 0; jj < 9; ++jj)
                    Cv = __builtin_fmaf(w[jj], pb[jj * D], Cv);
                Cv = (t < SEQ - P) ? Cv : -3.402823466e38f;   // poison -> never > bias
#pragma unroll
                for (int f = 0; f < NF; ++f)
                    cnt[f] += __popcll(__ballot(Cv > bs[f]));
            }
        }

#undef MRF_ITER2
#undef MRF_ITER
#undef MRF_MASKED

        // ---- write (cnt[] is already the wave total; no shuffle reduce) ----
        const bool full = ((k & 1) == PAD1);
        const float invT = full ? (1.0f / (float)SEQ) : (1.0f / (float)RANGE);
        const int pos = full ? ((k - PAD1) >> 1) : (42 + ((k - (1 - PAD1)) >> 1));
        const int colb = CBASE + pos * NF;
        if (lane == 0) {
#pragma unroll
            for (int f = 0; f < NF; ++f)
                out[(size_t)b * NFTOT + colb + f] = (float)cnt[f] * invT;
        }
    }
}

// NOTE: plain __launch_bounds__(64). Round-1/2 lesson: adding a min-waves/EU
// arg (64,4) made the allocator clamp to 64 VGPR and spill ~400 MB/dispatch
// to scratch. Round-3 lesson: VGPR must stay <=128 (occupancy bucket halves
// at 64/128/256); watch VGPR_Count on every change.
extern "C" __global__ void __launch_bounds__(64)
mrf_kernel(const float* __restrict__ x, const float* __restrict__ kw,
           const float* __restrict__ cc, const float* __restrict__ bias,
           float* __restrict__ out) {
    __shared__ __align__(16) float ybuf[SEQ];   // 8 KB per 1-wave block

    // XCD-chunked bijective swizzle (proven round 0): XCD x owns a contiguous
    // chunk of (b,i,s) with b slowest -> concurrent blocks on an XCD share ~1-2
    // b values -> x slices stay L2-resident. Round-1 measured the alternative
    // (i slowest): per-XCD working set = all 64 b slices > 4 MB L2 -> 1.75 GB
    // of L2 misses, 1.7x slower.
    constexpr int NGRID = NDIL * NBATCH * NSLOT;       // 19968
    constexpr int CHUNK = NGRID / NXCD;                // 2496
    const int blk = (blockIdx.x % NXCD) * CHUNK + blockIdx.x / NXCD;

    const int s = blk % NSLOT;
    const int rest = blk / NSLOT;
    const int i = rest % NDIL;              // dilation index
    const int b = rest / NDIL;              // batch index (slowest)
    const int lane = threadIdx.x & 63;

    const float* xb = x + (size_t)b * (NCH * SEQ);

    switch (i) {
#define MRF_CASE(I) case I: body<I>(kw, cc, bias, out, xb, ybuf, b, s, lane); break;
        MRF_CASE(0)  MRF_CASE(1)  MRF_CASE(2)  MRF_CASE(3)  MRF_CASE(4)
        MRF_CASE(5)  MRF_CASE(6)  MRF_CASE(7)  MRF_CASE(8)  MRF_CASE(9)
        MRF_CASE(10) MRF_CASE(11) MRF_CASE(12) MRF_CASE(13) MRF_CASE(14)
        MRF_CASE(15) MRF_CASE(16) MRF_CASE(17) MRF_CASE(18) MRF_CASE(19)
        MRF_CASE(20) MRF_CASE(21) MRF_CASE(22) MRF_CASE(23) MRF_CASE(24)
        MRF_CASE(25)
#undef MRF_CASE
    }
}

extern "C" void kernel_launch(void* const* d_in, const int* in_sizes, int n_in,
                              void* d_out, int out_size, void* d_ws, size_t ws_size,
                              hipStream_t stream) {
    (void)in_sizes; (void)n_in; (void)d_ws; (void)ws_size; (void)out_size;
    const float* x    = (const float*)d_in[0];
    const float* kw   = (const float*)d_in[1];
    const float* cc   = (const float*)d_in[2];
    const float* bias = (const float*)d_in[3];
    float* out = (float*)d_out;

    mrf_kernel<<<dim3(NDIL * NBATCH * NSLOT), dim3(64), 0, stream>>>(x, kw, cc, bias, out);
}

// Round 5
// 435.763 us; speedup vs baseline: 1.7122x; 1.7093x over previous
//
#include <hip/hip_runtime.h>

#define NKER 84
#define NCH 9
#define SEQ 2048
#define NBATCH 64
#define NDIL 26
#define NFTOT 9996
#define MAXNF 15
#define NSLOT 12
#define NXCD 8

// Static MiniRocket config for SEQ_LEN=2048, NUM_FEATURES=10000 (replicates numpy float64 logspace)
static constexpr int DILS[NDIL]   = {1,2,3,4,5,7,8,10,12,14,17,20,25,29,35,42,51,61,73,87,104,125,149,178,213,255};
static constexpr int NFDS[NDIL]   = {15,12,4,4,8,4,4,4,4,4,4,4,4,4,4,4,4,4,3,3,3,3,3,3,3,3};
static constexpr int CBASES[NDIL] = {0,1260,2268,2604,2940,3612,3948,4284,4620,4956,5292,5628,5964,6300,6636,6972,7308,7644,7980,8232,8484,8736,8988,9240,9492,9744};

// 2-float vector with 4-byte alignment: legal at odd dword offsets; compiler
// emits ds_read_b64 (aligned) or ds_read2_b32 offset0/offset1 (unaligned) —
// one DS instruction for two consecutive taps' elements either way.
// (Round-1/2 lesson: the b128 quad variant raised bank conflicts 3.7x and its
// register pressure triggered a 400MB scratch-spill catastrophe — stay at x2.)
typedef float f32x2u __attribute__((ext_vector_type(2), aligned(4)));

// Force a (known-uniform) float into an SGPR. v_fma/v_cmp accept one SGPR
// operand at full rate, so wave-uniform constants (w, bias) cost 0 VGPRs.
__device__ __forceinline__ float uniform_f(float v) {
    return __builtin_bit_cast(float, __builtin_amdgcn_readfirstlane(__builtin_bit_cast(int, v)));
}

template <int I>
__device__ __forceinline__ void body(const float* __restrict__ kw,
                                     const float* __restrict__ cc,
                                     const float* __restrict__ bias,
                                     float* __restrict__ out,
                                     const float* __restrict__ xb,   // x + b*NCH*SEQ
                                     float* __restrict__ y,
                                     int b, int slot, int lane) {
    constexpr int D = DILS[I];
    constexpr int NF = NFDS[I];
    constexpr int P = 4 * D;
    constexpr int PAD1 = I & 1;
    constexpr int CBASE = CBASES[I];
    constexpr int RANGE = SEQ - 2 * P;          // valid-region length (>0 for all D)
    // full-range loop split (compile-time): interior j has all taps in [0, SEQ) for every lane
    constexpr int JLO = (P + 63) / 64;                      // first fully-interior 64-iter
    constexpr int JHI = (SEQ - P - 64) / 64;                // last fully-interior 64-iter (incl)
    constexpr int NI  = (JHI + 1 > JLO) ? (JHI + 1 - JLO) : 0;   // # interior 64-iters
    constexpr int NI2 = NI / 2;                             // 128-el pair-iters
    constexpr bool IBR = (NI & 1) != 0;                     // one bridge 64-iter
    constexpr int JT0 = (JHI + 1 > JLO) ? (JHI + 1) : JLO;  // start of trailing boundary
    // valid-region decomposition: pairs + optional 64-bridge + clamped partial
    constexpr int MV2 = RANGE / 128;
    constexpr int TV1 = (RANGE - MV2 * 128) / 64;           // 0 or 1
    constexpr int REM = RANGE - MV2 * 128 - TV1 * 64;       // 0..63

    const float4* __restrict__ xb4 = (const float4*)xb;     // [NCH][SEQ/4]

    for (int k = slot; k < NKER; k += NSLOT) {
        // ---- per-kernel config (wave-uniform scalars) ----
        int mb = 0;
        for (int c = 0; c < NCH; ++c)
            if (cc[(I * NCH + c) * NKER + k] != 0.0f) mb |= (1 << c);
        mb = __builtin_amdgcn_readfirstlane(mb);

        int j0 = -1, j1 = -1, j2 = -1, no = 0;
        for (int j = 0; j < 9; ++j) {
            if (kw[k * 9 + j] > 0.0f) {
                if (no == 0) j0 = j; else if (no == 1) j1 = j; else j2 = j;
                ++no;
            }
        }
        j0 = __builtin_amdgcn_readfirstlane(j0);
        j1 = __builtin_amdgcn_readfirstlane(j1);
        j2 = __builtin_amdgcn_readfirstlane(j2);

        // tap weights and bias thresholds: wave-uniform -> force into SGPRs.
        // Round-3/4 lesson: the ballot+guard body naturally allocates 144 VGPR
        // (> the 128 occupancy boundary, m69) — scalarizing w/bs removes ~24
        // VGPRs of demand so the amdgpu_num_vgpr(128) cap binds without spill.
        float w[9];
#pragma unroll
        for (int jj = 0; jj < 9; ++jj)
            w[jj] = uniform_f((jj == j0 || jj == j1 || jj == j2) ? 2.0f : -1.0f);

        float bs[NF];
#pragma unroll
        for (int f = 0; f < NF; ++f)
            bs[f] = uniform_f(bias[(I * NKER + k) * MAXNF + f]);

        // ---- build y[t] = sum of masked channels, two half-SEQ passes ----
#pragma unroll
        for (int h = 0; h < 2; ++h) {
            float4 acc[SEQ / 512];
#pragma unroll
            for (int it = 0; it < SEQ / 512; ++it)
                acc[it] = make_float4(0.f, 0.f, 0.f, 0.f);
#pragma unroll
            for (int c = 0; c < NCH; ++c) {
                if (mb & (1 << c)) {
#pragma unroll
                    for (int it = 0; it < SEQ / 512; ++it) {
                        float4 v = xb4[c * (SEQ / 4) + h * (SEQ / 8) + it * 64 + lane];
                        acc[it].x += v.x; acc[it].y += v.y; acc[it].z += v.z; acc[it].w += v.w;
                    }
                }
            }
#pragma unroll
            for (int it = 0; it < SEQ / 512; ++it)
                ((float4*)y)[h * (SEQ / 8) + it * 64 + lane] = acc[it];
        }

        // wave-total counters via ballot+popcount: one v_cmp per (element,f),
        // accumulate on the scalar pipe, final shuffle reduce deleted.
        // Proven ~1.18x per-wave vs round 0 (rounds 3/4 occupancy-normalized).
        int cnt[NF];
#pragma unroll
        for (int f = 0; f < NF; ++f) cnt[f] = 0;

        // 128-el pair iter: lane handles t=TB+2*lane and t+1; per tap one 2-dword load
#define MRF_ITER2(TB) { \
            const int e0_ = (TB) + 2 * lane - 4 * D; \
            float CvA = 0.0f, CvB = 0.0f; \
            _Pragma("unroll") \
            for (int jj = 0; jj < 9; ++jj) { \
                f32x2u p_ = *(const f32x2u*)(y + e0_ + jj * D); \
                CvA = __builtin_fmaf(w[jj], p_.x, CvA); \
                CvB = __builtin_fmaf(w[jj], p_.y, CvB); \
            } \
            _Pragma("unroll") \
            for (int f = 0; f < NF; ++f) \
                cnt[f] += __popcll(__ballot(CvA > bs[f])) + __popcll(__ballot(CvB > bs[f])); }

        // 64-el unmasked iter
#define MRF_ITER(TB) { \
            const int t_ = (TB) + lane; \
            float Cv = 0.0f; \
            _Pragma("unroll") \
            for (int jj = 0; jj < 9; ++jj) \
                Cv = __builtin_fmaf(w[jj], y[t_ + (jj - 4) * D], Cv); \
            _Pragma("unroll") \
            for (int f = 0; f < NF; ++f) \
                cnt[f] += __popcll(__ballot(Cv > bs[f])); }

        // 64-el boundary iter: per-tap window is WAVE-UNIFORM in/out/straddle ->
        // scalar-branch skip (out), plain fma (in), clamped load only when straddling
#define MRF_MASKED(TB) { \
            const int t_ = (TB) + lane; \
            float Cv = 0.0f; \
            _Pragma("unroll") \
            for (int jj = 0; jj < 9; ++jj) { \
                const int lo_ = (TB) + (jj - 4) * D; \
                if (lo_ >= 0 && lo_ + 63 < SEQ) { \
                    Cv = __builtin_fmaf(w[jj], y[t_ + (jj - 4) * D], Cv); \
                } else if (lo_ + 63 >= 0 && lo_ < SEQ) { \
                    const int u_ = t_ + (jj - 4) * D; \
                    float v_ = y[u_ & (SEQ - 1)]; \
                    v_ = ((unsigned)u_ < (unsigned)SEQ) ? v_ : 0.0f; \
                    Cv = __builtin_fmaf(w[jj], v_, Cv); \
                } \
            } \
            _Pragma("unroll") \
            for (int f = 0; f < NF; ++f) \
                cnt[f] += __popcll(__ballot(Cv > bs[f])); }

        if ((k & 1) == PAD1) {
            // ===== full padded range [0, SEQ): masked lead, paired interior, masked trail =====
#pragma unroll 4
            for (int j = 0; j < JLO; ++j) MRF_MASKED(j * 64)
#pragma unroll 2
            for (int a = 0; a < NI2; ++a) MRF_ITER2(JLO * 64 + a * 128)
            if constexpr (IBR) MRF_ITER(JLO * 64 + NI2 * 128)
#pragma unroll 4
            for (int j = JT0; j < SEQ / 64; ++j) MRF_MASKED(j * 64)
        } else {
            // ===== valid region [P, SEQ-P): paired main, bridge, clamped partial =====
#pragma unroll 2
            for (int a = 0; a < MV2; ++a) MRF_ITER2(P + a * 128)
            if constexpr (TV1) MRF_ITER(P + MV2 * 128)
            if constexpr (REM != 0) {   // final partial, clamped reads, poisoned lanes
                const int t = P + MV2 * 128 + TV1 * 64 + lane;
                const int tr = (t < SEQ - P) ? t : (SEQ - P - 1);
                const float* __restrict__ pb = y + tr - 4 * D;
                float Cv = 0.0f;
#pragma unroll
                for (int jj = 0; jj < 9; ++jj)
                    Cv = __builtin_fmaf(w[jj], pb[jj * D], Cv);
                Cv = (t < SEQ - P) ? Cv : -3.402823466e38f;   // poison -> never > bias
#pragma unroll
                for (int f = 0; f < NF; ++f)
                    cnt[f] += __popcll(__ballot(Cv > bs[f]));
            }
        }

#undef MRF_ITER2
#undef MRF_ITER
#undef MRF_MASKED

        // ---- write (cnt[] is already the wave total; no shuffle reduce) ----
        const bool full = ((k & 1) == PAD1);
        const float invT = full ? (1.0f / (float)SEQ) : (1.0f / (float)RANGE);
        const int pos = full ? ((k - PAD1) >> 1) : (42 + ((k - (1 - PAD1)) >> 1));
        const int colb = CBASE + pos * NF;
        if (lane == 0) {
#pragma unroll
            for (int f = 0; f < NF; ++f)
                out[(size_t)b * NFTOT + colb + f] = (float)cnt[f] * invT;
        }
    }
}

// VGPR discipline (rounds 1-4): occupancy halves at 64/128/256 VGPR. The
// ballot body drifts to 144 naturally -> 11% occupancy. Hard-cap at the 128
// boundary; w/bs scalarization (above) lowers true demand so the cap binds
// by rescheduling, not spilling. Round-1 lesson: a cap FAR below demand
// ((64,4) vs ~160-reg body) spills catastrophically — cap at the boundary
// just above demand, never below. Spill sentinel: WRITE_SIZE >> 2.5 MB.
extern "C" __global__ void __launch_bounds__(64)
__attribute__((amdgpu_num_vgpr(128)))
mrf_kernel(const float* __restrict__ x, const float* __restrict__ kw,
           const float* __restrict__ cc, const float* __restrict__ bias,
           float* __restrict__ out) {
    __shared__ __align__(16) float ybuf[SEQ];   // 8 KB per 1-wave block

    // XCD-chunked bijective swizzle (proven round 0): XCD x owns a contiguous
    // chunk of (b,i,s) with b slowest -> concurrent blocks on an XCD share ~1-2
    // b values -> x slices stay L2-resident. Round-1 measured the alternative
    // (i slowest): per-XCD working set = all 64 b slices > 4 MB L2 -> 1.75 GB
    // of L2 misses, 1.7x slower.
    constexpr int NGRID = NDIL * NBATCH * NSLOT;       // 19968
    constexpr int CHUNK = NGRID / NXCD;                // 2496
    const int blk = (blockIdx.x % NXCD) * CHUNK + blockIdx.x / NXCD;

    const int s = blk % NSLOT;
    const int rest = blk / NSLOT;
    const int i = rest % NDIL;              // dilation index
    const int b = rest / NDIL;              // batch index (slowest)
    const int lane = threadIdx.x & 63;

    const float* xb = x + (size_t)b * (NCH * SEQ);

    switch (i) {
#define MRF_CASE(I) case I: body<I>(kw, cc, bias, out, xb, ybuf, b, s, lane); break;
        MRF_CASE(0)  MRF_CASE(1)  MRF_CASE(2)  MRF_CASE(3)  MRF_CASE(4)
        MRF_CASE(5)  MRF_CASE(6)  MRF_CASE(7)  MRF_CASE(8)  MRF_CASE(9)
        MRF_CASE(10) MRF_CASE(11) MRF_CASE(12) MRF_CASE(13) MRF_CASE(14)
        MRF_CASE(15) MRF_CASE(16) MRF_CASE(17) MRF_CASE(18) MRF_CASE(19)
        MRF_CASE(20) MRF_CASE(21) MRF_CASE(22) MRF_CASE(23) MRF_CASE(24)
        MRF_CASE(25)
#undef MRF_CASE
    }
}

extern "C" void kernel_launch(void* const* d_in, const int* in_sizes, int n_in,
                              void* d_out, int out_size, void* d_ws, size_t ws_size,
                              hipStream_t stream) {
    (void)in_sizes; (void)n_in; (void)d_ws; (void)ws_size; (void)out_size;
    const float* x    = (const float*)d_in[0];
    const float* kw   = (const float*)d_in[1];
    const float* cc   = (const float*)d_in[2];
    const float* bias = (const float*)d_in[3];
    float* out = (float*)d_out;

    mrf_kernel<<<dim3(NDIL * NBATCH * NSLOT), dim3(64), 0, stream>>>(x, kw, cc, bias, out);
}